// Round 10
// baseline (154.682 us; speedup 1.0000x reference)
//
#include <hip/hip_runtime.h>

// bicon_loss R10: direct-to-LDS DMA staging (global_load_lds).
// R4-R9 invariant: time == FETCH / ~1.7 TB/s; compiler refuses >4-6 VGPR
// load bursts (VGPR pinned 64-88), so outstanding-bytes/CU stays tiny.
// global_load_lds has NO VGPR destination => 12 staging loads + 9 direct
// loads per thread all in flight until the barrier drain (m97 pattern).
// Tile = 2 rows + (W+64)-halo staged fp32 in 48KB LDS, 3 blocks/CU.

#define EPSF 1e-7f

constexpr int B = 16, H = 352, W = 352;
constexpr int HW = H * W;               // 123904
constexpr int TILE_PX = 704;            // 2 rows per block
constexpr int TILES = HW / TILE_PX;     // 176 (exact)
constexpr int NBLK = B * TILES;         // 2816
constexpr int TILE_Q = TILE_PX / 4;     // 176 quads per block
constexpr int HALO = 416;               // >= W+1, multiple of 4
constexpr int STAGE_PX = TILE_PX + 2 * HALO;   // 1536 px per channel
constexpr int STAGE_Q  = STAGE_PX / 4;         // 384 (= 6 waves exactly)
constexpr int SITER = 8 * STAGE_Q / 256;       // 12 staging DMAs per thread

typedef float f4 __attribute__((ext_vector_type(4)));
typedef int   i4 __attribute__((ext_vector_type(4)));

__device__ __forceinline__ float rcpf(float x) { return __builtin_amdgcn_rcpf(x); }

__device__ __forceinline__ f4 sigmoid4(f4 x) {
    f4 r;
    r.x = rcpf(1.0f + __expf(-x.x));
    r.y = rcpf(1.0f + __expf(-x.y));
    r.z = rcpf(1.0f + __expf(-x.z));
    r.w = rcpf(1.0f + __expf(-x.w));
    return r;
}
__device__ __forceinline__ f4 max4(f4 a, f4 b) {
    f4 r; r.x=fmaxf(a.x,b.x); r.y=fmaxf(a.y,b.y); r.z=fmaxf(a.z,b.z); r.w=fmaxf(a.w,b.w); return r;
}
__device__ __forceinline__ f4 min4(f4 a, f4 b) {
    f4 r; r.x=fminf(a.x,b.x); r.y=fminf(a.y,b.y); r.z=fminf(a.z,b.z); r.w=fminf(a.w,b.w); return r;
}
__device__ __forceinline__ f4 sel4(i4 m, f4 a, f4 b) {
    f4 r; r.x=m.x?a.x:b.x; r.y=m.y?a.y:b.y; r.z=m.z?a.z:b.z; r.w=m.w?a.w:b.w; return r;
}
// element-granular 4-wide f32 read from LDS (4B-aligned)
__device__ __forceinline__ f4 rd4f(const float* p) {
    f4 r; r.x=p[0]; r.y=p[1]; r.z=p[2]; r.w=p[3]; return r;
}

// 16B global -> LDS DMA: no VGPR destination, stays in flight until waitcnt.
// LDS dest semantics: wave-uniform base + lane*16 (our layout matches exactly).
__device__ __forceinline__ void load_lds16(const float* g, float* l) {
    __builtin_amdgcn_global_load_lds(
        (const __attribute__((address_space(1))) unsigned int*)g,
        (__attribute__((address_space(3))) unsigned int*)l, 16, 0, 0);
}

__device__ __forceinline__ float finish_pixel(float glo, float pmin, int sc,
                                              float t, float cp, float ba, float bb) {
    const float edge = (sc < 8 && sc > 0) ? 1.0f : 0.0f;
    float dec = glo * (1.0f - edge) + (1.0f - pmin) * edge;
    dec = fminf(fmaxf(dec, EPSF), 1.0f - EPSF);
    const float de = -(t * __logf(dec) + (1.0f - t) * __logf(1.0f - dec));
    return de - 0.8f * __logf(cp) - 0.2f * (__logf(ba) + __logf(bb));
}

__global__ __launch_bounds__(256) void bicon_loss_kernel(
    const float* __restrict__ c_map,    // [B,8,H,W]
    const float* __restrict__ target,   // [B,1,H,W]
    const int*   __restrict__ con,      // [B,8,H,W] in {0,1}
    float* __restrict__ ws)             // [NBLK] partial sums
{
    __shared__ float Lr[8 * STAGE_PX];  // 49152 B raw c_map (fp32)
    __shared__ float wsum[4];

    const int blk  = blockIdx.x;
    const int b    = blk / TILES;
    const int tile = blk - b * TILES;
    const int s    = tile * TILE_PX;    // first pixel of tile (row-aligned)
    const int s0   = s - HALO;

    const float* __restrict__ cmb = c_map + (size_t)b * 8 * HW;
    const int*   __restrict__ cnb = con   + (size_t)b * 8 * HW;
    const float* __restrict__ tgb = target + (size_t)b * HW;

    // -------- staging: 12 back-to-back LDS DMAs, no VGPR deps --------
    #pragma unroll
    for (int k = 0; k < SITER; ++k) {
        const int q   = k * 256 + threadIdx.x;   // 0..3071
        const int ch  = q / STAGE_Q;
        const int idx = q - ch * STAGE_Q;
        int px = s0 + idx * 4;
        px = px < 0 ? 0 : (px > HW - 4 ? HW - 4 : px);
        load_lds16(cmb + ch * HW + px, &Lr[q * 4]);
    }

    // -------- direct loads (issued pre-barrier, in flight with DMAs) ----
    const bool act = threadIdx.x < TILE_Q;
    const int  qi  = threadIdx.x;
    const int  gp  = s + qi * 4;
    i4 g0{}, g1{}, g2{}, g3{}, g4{}, g5{}, g6{}, g7{};
    f4 t4{};
    if (act) {
        g0 = *(const i4*)(cnb + 0 * HW + gp);
        g1 = *(const i4*)(cnb + 1 * HW + gp);
        g2 = *(const i4*)(cnb + 2 * HW + gp);
        g3 = *(const i4*)(cnb + 3 * HW + gp);
        g4 = *(const i4*)(cnb + 4 * HW + gp);
        g5 = *(const i4*)(cnb + 5 * HW + gp);
        g6 = *(const i4*)(cnb + 6 * HW + gp);
        g7 = *(const i4*)(cnb + 7 * HW + gp);
        t4 = *(const f4*)(tgb + gp);
    }

    __syncthreads();   // drains vmcnt(0): all DMAs + direct loads complete

    // -------- compute: 176 quads (threads 0..175) --------
    float part = 0.0f;
    if (act) {
        const int y   = gp / W;
        const int xq4 = (gp - y * W) >> 2;
        const float lm = (xq4 == 0)         ? 0.0f : 1.0f;
        const float rm = (xq4 == W / 4 - 1) ? 0.0f : 1.0f;
        const float tm = (y == 0)           ? 0.0f : 1.0f;
        const float bm = (y == H - 1)       ? 0.0f : 1.0f;
        const int l0 = HALO + qi * 4;        // staged index of gp (16B-aligned)

        // centers (aligned b128 reads + sigmoid)
        const f4 p0 = sigmoid4(*(const f4*)&Lr[0 * STAGE_PX + l0]);
        const f4 p1 = sigmoid4(*(const f4*)&Lr[1 * STAGE_PX + l0]);
        const f4 p2 = sigmoid4(*(const f4*)&Lr[2 * STAGE_PX + l0]);
        const f4 p3 = sigmoid4(*(const f4*)&Lr[3 * STAGE_PX + l0]);
        const f4 p4 = sigmoid4(*(const f4*)&Lr[4 * STAGE_PX + l0]);
        const f4 p5 = sigmoid4(*(const f4*)&Lr[5 * STAGE_PX + l0]);
        const f4 p6 = sigmoid4(*(const f4*)&Lr[6 * STAGE_PX + l0]);
        const f4 p7 = sigmoid4(*(const f4*)&Lr[7 * STAGE_PX + l0]);
        // neighbors: dir i reads channel 7-i at offset -dy*W-dx
        const f4 n0 = sigmoid4(rd4f(&Lr[7 * STAGE_PX + l0 - W - 1]));
        const f4 n1 = sigmoid4(*(const f4*)&Lr[6 * STAGE_PX + l0 - W]);  // -352: 16B-aligned
        const f4 n2 = sigmoid4(rd4f(&Lr[5 * STAGE_PX + l0 - W + 1]));
        const f4 n3 = sigmoid4(rd4f(&Lr[4 * STAGE_PX + l0 - 1]));
        const f4 n4 = sigmoid4(rd4f(&Lr[3 * STAGE_PX + l0 + 1]));
        const f4 n5 = sigmoid4(rd4f(&Lr[2 * STAGE_PX + l0 + W - 1]));
        const f4 n6 = sigmoid4(*(const f4*)&Lr[1 * STAGE_PX + l0 + W]);
        const f4 n7 = sigmoid4(rd4f(&Lr[0 * STAGE_PX + l0 + W + 1]));

        f4 conprod = {1.f,1.f,1.f,1.f};
        f4 biA     = {1.f,1.f,1.f,1.f};
        f4 biB     = {1.f,1.f,1.f,1.f};
        f4 glo     = {-1e30f,-1e30f,-1e30f,-1e30f};
        f4 pmin    = { 1e30f, 1e30f, 1e30f, 1e30f};

#define DIR(P, G, S, DX, RMASK, BI) {                                         \
        f4 sv = (S);                                                          \
        sv *= (RMASK);                                                        \
        if ((DX) == 1)  sv.x *= lm;                                           \
        if ((DX) == -1) sv.w *= rm;                                           \
        const f4 v = (P) * sv;                                                \
        glo  = max4(glo,  v);                                                 \
        pmin = min4(pmin, v);                                                 \
        conprod *= sel4((G), (P), 1.0f - (P));                                \
        BI *= sel4((G), max4(v, (f4){EPSF,EPSF,EPSF,EPSF}), 1.0f - v);        \
    }
        DIR(p0, g0, n0,  1, tm,   biA)
        DIR(p1, g1, n1,  0, tm,   biA)
        DIR(p2, g2, n2, -1, tm,   biA)
        DIR(p3, g3, n3,  1, 1.0f, biA)
        DIR(p4, g4, n4, -1, 1.0f, biB)
        DIR(p5, g5, n5,  1, bm,   biB)
        DIR(p6, g6, n6,  0, bm,   biB)
        DIR(p7, g7, n7, -1, bm,   biB)
#undef DIR

        const i4 sc = g0 + g1 + g2 + g3 + g4 + g5 + g6 + g7;
        part = finish_pixel(glo.x, pmin.x, sc.x, t4.x, conprod.x, biA.x, biB.x)
             + finish_pixel(glo.y, pmin.y, sc.y, t4.y, conprod.y, biA.y, biB.y)
             + finish_pixel(glo.z, pmin.z, sc.z, t4.z, conprod.z, biA.z, biB.z)
             + finish_pixel(glo.w, pmin.w, sc.w, t4.w, conprod.w, biA.w, biB.w);
    }

    // wave64 shuffle reduction
    #pragma unroll
    for (int off = 32; off > 0; off >>= 1)
        part += __shfl_down(part, off, 64);

    const int lane = threadIdx.x & 63;
    const int wid  = threadIdx.x >> 6;
    if (lane == 0) wsum[wid] = part;
    __syncthreads();
    if (threadIdx.x == 0)
        ws[blockIdx.x] = wsum[0] + wsum[1] + wsum[2] + wsum[3];
}

// Stage 2: one block sums the NBLK partials and writes the scalar output.
__global__ __launch_bounds__(256) void reduce_partials_kernel(
    const float* __restrict__ ws, float* __restrict__ out)
{
    float s = 0.0f;
    for (int i = threadIdx.x; i < NBLK; i += 256) s += ws[i];
    #pragma unroll
    for (int off = 32; off > 0; off >>= 1)
        s += __shfl_down(s, off, 64);
    __shared__ float wsum[4];
    const int lane = threadIdx.x & 63;
    const int wid  = threadIdx.x >> 6;
    if (lane == 0) wsum[wid] = s;
    __syncthreads();
    if (threadIdx.x == 0) out[0] = wsum[0] + wsum[1] + wsum[2] + wsum[3];
}

extern "C" void kernel_launch(void* const* d_in, const int* in_sizes, int n_in,
                              void* d_out, int out_size, void* d_ws, size_t ws_size,
                              hipStream_t stream) {
    const float* c_map  = (const float*)d_in[0];
    const float* target = (const float*)d_in[1];
    const int*   con    = (const int*)d_in[2];
    float* out = (float*)d_out;
    float* ws  = (float*)d_ws;   // NBLK floats

    bicon_loss_kernel<<<NBLK, 256, 0, stream>>>(c_map, target, con, ws);
    reduce_partials_kernel<<<1, 256, 0, stream>>>(ws, out);
}

// Round 11
// 153.199 us; speedup vs baseline: 1.0097x; 1.0097x over previous
//
#include <hip/hip_runtime.h>

// bicon_loss R11: asymmetric per-channel halo staging (DMA), 4-row tiles.
// Invariant found R6/R10: vmem-volume / time == ~4.5 TB/s regardless of
// structure => cut volume. Dir i reads ch 7-i at -dy*W-dx, so each channel
// needs halo on ONE side only: staged c_map = 1.19x ideal (was 2.18x in
// R10). Total vmem 209 -> 147 MB (floor = 135). Keep R10's global_load_lds
// MLP. LDS 52.3 KB -> 3 blocks/CU.

#define EPSF 1e-7f

constexpr int B = 16, H = 352, W = 352;
constexpr int HW = H * W;                // 123904
constexpr int TILE_PX = 1408;            // 4 rows per block
constexpr int TILES = HW / TILE_PX;      // 88 (exact)
constexpr int NBLK = B * TILES;          // 1408
constexpr int TILE_Q = TILE_PX / 4;      // 352 quads per block

// Per-channel staged range (px, relative to tile start s), 16B-aligned.
// ch0..2 need [0, TILE+W+1) ; ch3 [0,TILE+1) ; ch4 [-1,TILE) ;
// ch5..7 need [-(W+1), TILE).
__device__ __constant__ // (constexpr arrays below are compile-time folded)
constexpr int CSTART[8] = {    0,    0,    0,    0,   -4, -352, -352, -356};
constexpr int CQCNT [8] = {  441,  440,  440,  353,  353,  440,  440,  441};
constexpr int CLBASE[8] = {    0, 1764, 3524, 5284, 6696, 8108, 9868, 11628};
constexpr int STAGE_TOT = 13392;         // px ; * 4B = 53568 B LDS

typedef float f4 __attribute__((ext_vector_type(4)));
typedef int   i4 __attribute__((ext_vector_type(4)));

__device__ __forceinline__ float rcpf(float x) { return __builtin_amdgcn_rcpf(x); }

__device__ __forceinline__ f4 sigmoid4(f4 x) {
    f4 r;
    r.x = rcpf(1.0f + __expf(-x.x));
    r.y = rcpf(1.0f + __expf(-x.y));
    r.z = rcpf(1.0f + __expf(-x.z));
    r.w = rcpf(1.0f + __expf(-x.w));
    return r;
}
__device__ __forceinline__ f4 max4(f4 a, f4 b) {
    f4 r; r.x=fmaxf(a.x,b.x); r.y=fmaxf(a.y,b.y); r.z=fmaxf(a.z,b.z); r.w=fmaxf(a.w,b.w); return r;
}
__device__ __forceinline__ f4 min4(f4 a, f4 b) {
    f4 r; r.x=fminf(a.x,b.x); r.y=fminf(a.y,b.y); r.z=fminf(a.z,b.z); r.w=fminf(a.w,b.w); return r;
}
__device__ __forceinline__ f4 sel4(i4 m, f4 a, f4 b) {
    f4 r; r.x=m.x?a.x:b.x; r.y=m.y?a.y:b.y; r.z=m.z?a.z:b.z; r.w=m.w?a.w:b.w; return r;
}
__device__ __forceinline__ f4 rd4f(const float* p) {   // element-granular LDS read
    f4 r; r.x=p[0]; r.y=p[1]; r.z=p[2]; r.w=p[3]; return r;
}

// 16B global -> LDS DMA (no VGPR destination; respects exec mask).
__device__ __forceinline__ void load_lds16(const float* g, float* l) {
    __builtin_amdgcn_global_load_lds(
        (const __attribute__((address_space(1))) unsigned int*)g,
        (__attribute__((address_space(3))) unsigned int*)l, 16, 0, 0);
}

__device__ __forceinline__ float finish_pixel(float glo, float pmin, int sc,
                                              float t, float cp, float ba, float bb) {
    const float edge = (sc < 8 && sc > 0) ? 1.0f : 0.0f;
    float dec = glo * (1.0f - edge) + (1.0f - pmin) * edge;
    dec = fminf(fmaxf(dec, EPSF), 1.0f - EPSF);
    const float de = -(t * __logf(dec) + (1.0f - t) * __logf(1.0f - dec));
    return de - 0.8f * __logf(cp) - 0.2f * (__logf(ba) + __logf(bb));
}

__global__ __launch_bounds__(256) void bicon_loss_kernel(
    const float* __restrict__ c_map,    // [B,8,H,W]
    const float* __restrict__ target,   // [B,1,H,W]
    const int*   __restrict__ con,      // [B,8,H,W] in {0,1}
    float* __restrict__ ws)             // [NBLK] partial sums
{
    __shared__ float Lr[STAGE_TOT];     // 53568 B staged raw c_map
    __shared__ float wsum[4];

    const int blk  = blockIdx.x;
    const int b    = blk / TILES;
    const int tile = blk - b * TILES;
    const int s    = tile * TILE_PX;    // first pixel of tile (row-aligned)

    const float* __restrict__ cmb = c_map + (size_t)b * 8 * HW;
    const int*   __restrict__ cnb = con   + (size_t)b * 8 * HW;
    const float* __restrict__ tgb = target + (size_t)b * HW;

    // -------- staging: per-channel asymmetric ranges, 16 DMA steps --------
    // Clamped px at batch top/bottom stage duplicate rows; every such entry
    // is only consumed under a tm/bm/lm/rm zero mask.
    #pragma unroll
    for (int c = 0; c < 8; ++c) {
        #pragma unroll
        for (int k = 0; k < 2; ++k) {
            const int iq = k * 256 + threadIdx.x;
            if (iq < CQCNT[c]) {
                int px = s + CSTART[c] + iq * 4;
                px = px < 0 ? 0 : (px > HW - 4 ? HW - 4 : px);
                load_lds16(cmb + c * HW + px, &Lr[CLBASE[c] + iq * 4]);
            }
        }
    }

    // -------- direct loads (pre-barrier, in flight with DMAs) --------
    const int qi1 = threadIdx.x;            // slot 1: always active
    const int qi2 = 256 + threadIdx.x;      // slot 2: threads 0..95
    const bool act2 = qi2 < TILE_Q;
    const int gp1 = s + qi1 * 4;
    const int gp2 = s + qi2 * 4;
    const i4 a0 = *(const i4*)(cnb + 0 * HW + gp1);
    const i4 a1 = *(const i4*)(cnb + 1 * HW + gp1);
    const i4 a2 = *(const i4*)(cnb + 2 * HW + gp1);
    const i4 a3 = *(const i4*)(cnb + 3 * HW + gp1);
    const i4 a4 = *(const i4*)(cnb + 4 * HW + gp1);
    const i4 a5 = *(const i4*)(cnb + 5 * HW + gp1);
    const i4 a6 = *(const i4*)(cnb + 6 * HW + gp1);
    const i4 a7 = *(const i4*)(cnb + 7 * HW + gp1);
    const f4 ta = *(const f4*)(tgb + gp1);
    i4 b0{}, b1{}, b2{}, b3{}, b4{}, b5{}, b6{}, b7{};
    f4 tb{};
    if (act2) {
        b0 = *(const i4*)(cnb + 0 * HW + gp2);
        b1 = *(const i4*)(cnb + 1 * HW + gp2);
        b2 = *(const i4*)(cnb + 2 * HW + gp2);
        b3 = *(const i4*)(cnb + 3 * HW + gp2);
        b4 = *(const i4*)(cnb + 4 * HW + gp2);
        b5 = *(const i4*)(cnb + 5 * HW + gp2);
        b6 = *(const i4*)(cnb + 6 * HW + gp2);
        b7 = *(const i4*)(cnb + 7 * HW + gp2);
        tb = *(const f4*)(tgb + gp2);
    }

    __syncthreads();   // drains all DMAs + direct loads

    // -------- compute --------
    float part = 0.0f;
#define QUAD(QI, GP, G0,G1,G2,G3,G4,G5,G6,G7, T4) {                           \
        const int q4  = (QI) * 4;                                             \
        const int y   = (GP) / W;                                             \
        const int xq4 = ((GP) - y * W) >> 2;                                  \
        const float lm = (xq4 == 0)         ? 0.0f : 1.0f;                    \
        const float rm = (xq4 == W / 4 - 1) ? 0.0f : 1.0f;                    \
        const float tm = (y == 0)           ? 0.0f : 1.0f;                    \
        const float bm = (y == H - 1)       ? 0.0f : 1.0f;                    \
        /* centers: l = CLBASE[c] - CSTART[c] + q4 (all 16B-aligned) */       \
        const f4 p0 = sigmoid4(*(const f4*)&Lr[    0 + q4]);                  \
        const f4 p1 = sigmoid4(*(const f4*)&Lr[ 1764 + q4]);                  \
        const f4 p2 = sigmoid4(*(const f4*)&Lr[ 3524 + q4]);                  \
        const f4 p3 = sigmoid4(*(const f4*)&Lr[ 5284 + q4]);                  \
        const f4 p4 = sigmoid4(*(const f4*)&Lr[ 6700 + q4]);                  \
        const f4 p5 = sigmoid4(*(const f4*)&Lr[ 8460 + q4]);                  \
        const f4 p6 = sigmoid4(*(const f4*)&Lr[10220 + q4]);                  \
        const f4 p7 = sigmoid4(*(const f4*)&Lr[11984 + q4]);                  \
        /* neighbors: dir i = ch 7-i at center_l + OFF */                     \
        const f4 n0 = sigmoid4(rd4f(&Lr[11631 + q4]));                        \
        const f4 n1 = sigmoid4(*(const f4*)&Lr[ 9868 + q4]);                  \
        const f4 n2 = sigmoid4(rd4f(&Lr[ 8109 + q4]));                        \
        const f4 n3 = sigmoid4(rd4f(&Lr[ 6699 + q4]));                        \
        const f4 n4 = sigmoid4(rd4f(&Lr[ 5285 + q4]));                        \
        const f4 n5 = sigmoid4(rd4f(&Lr[ 3875 + q4]));                        \
        const f4 n6 = sigmoid4(*(const f4*)&Lr[ 2116 + q4]);                  \
        const f4 n7 = sigmoid4(rd4f(&Lr[  353 + q4]));                        \
        f4 conprod = {1.f,1.f,1.f,1.f};                                       \
        f4 biA     = {1.f,1.f,1.f,1.f};                                       \
        f4 biB     = {1.f,1.f,1.f,1.f};                                       \
        f4 glo     = {-1e30f,-1e30f,-1e30f,-1e30f};                           \
        f4 pmin    = { 1e30f, 1e30f, 1e30f, 1e30f};                           \
        DIRX(p0, G0, n0,  1, tm,   biA)                                       \
        DIRX(p1, G1, n1,  0, tm,   biA)                                       \
        DIRX(p2, G2, n2, -1, tm,   biA)                                       \
        DIRX(p3, G3, n3,  1, 1.0f, biA)                                       \
        DIRX(p4, G4, n4, -1, 1.0f, biB)                                       \
        DIRX(p5, G5, n5,  1, bm,   biB)                                       \
        DIRX(p6, G6, n6,  0, bm,   biB)                                       \
        DIRX(p7, G7, n7, -1, bm,   biB)                                       \
        const i4 sc = G0 + G1 + G2 + G3 + G4 + G5 + G6 + G7;                  \
        part += finish_pixel(glo.x, pmin.x, sc.x, (T4).x, conprod.x, biA.x, biB.x) \
              + finish_pixel(glo.y, pmin.y, sc.y, (T4).y, conprod.y, biA.y, biB.y) \
              + finish_pixel(glo.z, pmin.z, sc.z, (T4).z, conprod.z, biA.z, biB.z) \
              + finish_pixel(glo.w, pmin.w, sc.w, (T4).w, conprod.w, biA.w, biB.w); \
    }
#define DIRX(P, G, S, DX, RMASK, BI) {                                        \
        f4 sv = (S);                                                          \
        sv *= (RMASK);                                                        \
        if ((DX) == 1)  sv.x *= lm;                                           \
        if ((DX) == -1) sv.w *= rm;                                           \
        const f4 v = (P) * sv;                                                \
        glo  = max4(glo,  v);                                                 \
        pmin = min4(pmin, v);                                                 \
        conprod *= sel4((G), (P), 1.0f - (P));                                \
        BI *= sel4((G), max4(v, (f4){EPSF,EPSF,EPSF,EPSF}), 1.0f - v);        \
    }

    QUAD(qi1, gp1, a0,a1,a2,a3,a4,a5,a6,a7, ta)
    if (act2) {
        QUAD(qi2, gp2, b0,b1,b2,b3,b4,b5,b6,b7, tb)
    }
#undef DIRX
#undef QUAD

    // wave64 shuffle reduction
    #pragma unroll
    for (int off = 32; off > 0; off >>= 1)
        part += __shfl_down(part, off, 64);

    const int lane = threadIdx.x & 63;
    const int wid  = threadIdx.x >> 6;
    if (lane == 0) wsum[wid] = part;
    __syncthreads();
    if (threadIdx.x == 0)
        ws[blockIdx.x] = wsum[0] + wsum[1] + wsum[2] + wsum[3];
}

// Stage 2: one block sums the NBLK partials and writes the scalar output.
__global__ __launch_bounds__(256) void reduce_partials_kernel(
    const float* __restrict__ ws, float* __restrict__ out)
{
    float s = 0.0f;
    for (int i = threadIdx.x; i < NBLK; i += 256) s += ws[i];
    #pragma unroll
    for (int off = 32; off > 0; off >>= 1)
        s += __shfl_down(s, off, 64);
    __shared__ float wsum[4];
    const int lane = threadIdx.x & 63;
    const int wid  = threadIdx.x >> 6;
    if (lane == 0) wsum[wid] = s;
    __syncthreads();
    if (threadIdx.x == 0) out[0] = wsum[0] + wsum[1] + wsum[2] + wsum[3];
}

extern "C" void kernel_launch(void* const* d_in, const int* in_sizes, int n_in,
                              void* d_out, int out_size, void* d_ws, size_t ws_size,
                              hipStream_t stream) {
    const float* c_map  = (const float*)d_in[0];
    const float* target = (const float*)d_in[1];
    const int*   con    = (const int*)d_in[2];
    float* out = (float*)d_out;
    float* ws  = (float*)d_ws;   // NBLK floats

    bicon_loss_kernel<<<NBLK, 256, 0, stream>>>(c_map, target, con, ws);
    reduce_partials_kernel<<<1, 256, 0, stream>>>(ws, out);
}